// Round 23
// baseline (228.816 us; speedup 1.0000x reference)
//
#include <hip/hip_runtime.h>

#define E_TOTAL 200000
#define NPAIR 100000
#define N_NODES 10000
#define OUTD 5
#define NTILES 3125           // 200000 / 64 exactly; 32 pairs per tile
#define WP_USHORTS 532480     // W0p (262144) + W1p (262144) + W2p (8192)
#define YAB_USHORTS 10240000  // 10000 nodes x 1024 (ya|yb) bf16
#define WS_Y ((size_t)(WP_USHORTS + YAB_USHORTS) * 2)
// sort extras (bytes, after yab): hist u32[10240] | pperm u32[100000]
#define WS_SORT (WS_Y + 40960 + 400000)

typedef __attribute__((ext_vector_type(4))) float f32x4;
typedef __attribute__((ext_vector_type(16))) float f32x16;
typedef __attribute__((ext_vector_type(8))) __bf16 bf16x8;

static __device__ __forceinline__ unsigned short f2bf(float f) {
  union { float f; unsigned u; } v; v.f = f;
  unsigned u = v.u;
  unsigned r = (u + 0x7FFFu + ((u >> 16) & 1u)) >> 16;   // RNE
  return (unsigned short)r;
}
static __device__ __forceinline__ unsigned short f2bf_cast(float f) {
  __bf16 h = (__bf16)f;                                   // HW cvt, RNE
  return __builtin_bit_cast(unsigned short, h);
}
static __device__ __forceinline__ unsigned addrelu2(unsigned a, unsigned b) {
  float alo = __builtin_bit_cast(float, a << 16);
  float ahi = __builtin_bit_cast(float, a & 0xffff0000u);
  float blo = __builtin_bit_cast(float, b << 16);
  float bhi = __builtin_bit_cast(float, b & 0xffff0000u);
  float slo = fmaxf(alo + blo, 0.f);
  float shi = fmaxf(ahi + bhi, 0.f);
  return (unsigned)f2bf_cast(slo) | ((unsigned)f2bf_cast(shi) << 16);
}

// ---------------------------------------------------------------------------
// Pack W0,W1 [512x512] into 32x32x16-bf16 fragment order; W2 padded N=16.
// One thread = one 16B chunk (8 coalesced f32 reads -> 1 uint4 store).
// Folds hist zeroing (tid in [66560,76800)).
// ---------------------------------------------------------------------------
__global__ __launch_bounds__(256) void pack_weights(
    const float* __restrict__ W0, const float* __restrict__ W1,
    const float* __restrict__ W2, unsigned short* __restrict__ wp,
    unsigned* __restrict__ hist) {
  const int tid = blockIdx.x * 256 + threadIdx.x;
  if (tid < 65536) {
    const int sel = tid >> 15;
    const int r = tid & 32767;
    const int ntile = r >> 11;
    const int ks = (r >> 6) & 31;
    const int lane = r & 63;
    const float* W = sel ? W1 : W0;
    const int n = ntile * 32 + (lane & 31);
    const int kb = ks * 16 + ((lane >> 5) << 3);
    uint4 pk;
    pk.x = (unsigned)f2bf(W[(kb + 0) * 512 + n]) | ((unsigned)f2bf(W[(kb + 1) * 512 + n]) << 16);
    pk.y = (unsigned)f2bf(W[(kb + 2) * 512 + n]) | ((unsigned)f2bf(W[(kb + 3) * 512 + n]) << 16);
    pk.z = (unsigned)f2bf(W[(kb + 4) * 512 + n]) | ((unsigned)f2bf(W[(kb + 5) * 512 + n]) << 16);
    pk.w = (unsigned)f2bf(W[(kb + 6) * 512 + n]) | ((unsigned)f2bf(W[(kb + 7) * 512 + n]) << 16);
    *(uint4*)(wp + (size_t)sel * 262144 +
              (((size_t)(ntile * 32 + ks) * 64 + lane) << 3)) = pk;
  } else if (tid < 66560) {                    // W2 padded N=5 -> 16
    const int r = tid - 65536;
    const int k0 = r >> 6, lane = r & 63;
    const int kb = k0 * 32 + ((lane >> 4) << 3);
    const int n = lane & 15;
    unsigned short v[8];
#pragma unroll
    for (int j = 0; j < 8; ++j)
      v[j] = (n < OUTD) ? f2bf(W2[(kb + j) * OUTD + n]) : (unsigned short)0;
    uint4 pk;
    pk.x = (unsigned)v[0] | ((unsigned)v[1] << 16);
    pk.y = (unsigned)v[2] | ((unsigned)v[3] << 16);
    pk.z = (unsigned)v[4] | ((unsigned)v[5] << 16);
    pk.w = (unsigned)v[6] | ((unsigned)v[7] << 16);
    *(uint4*)(wp + 524288 + (((size_t)k0 * 64 + lane) << 3)) = pk;
  } else if (tid < 76800) {
    if (hist) hist[tid - 66560] = 0u;
  }
}

// ---------------------------------------------------------------------------
// Node-level layer-0 precompute; packed uint2 stores.
// yab[node][0..512) = x@W0a + b0 ; [512..1024) = x@W0b.
// ---------------------------------------------------------------------------
__global__ __launch_bounds__(256, 2) void node_mlp0(
    const float* __restrict__ x, const float* __restrict__ b0,
    const unsigned short* __restrict__ wp, unsigned short* __restrict__ yab) {
  __shared__ uint4 ldsv2[1024];               // 16384 B
  unsigned char* lds = (unsigned char*)ldsv2;
  const int tid = threadIdx.x;
  const int lane = tid & 63;
  const int w = tid >> 6;
  const int l31 = lane & 31, h = lane >> 5;
  const int n0 = blockIdx.x * 32;

  {
    const int r = tid >> 3, p = tid & 7;
    int node = n0 + r; if (node > N_NODES - 1) node = N_NODES - 1;
    const float* s = x + (size_t)node * 256 + p * 32;
    const unsigned rowb = (unsigned)r * 512;
    const unsigned sx = (unsigned)((r & 7) << 4);
#pragma unroll
    for (int c = 0; c < 4; ++c) {
      const int kk = (c + p) & 3;
      const float4 f0 = *(const float4*)(s + kk * 8);
      const float4 f1 = *(const float4*)(s + kk * 8 + 4);
      uint4 pk;
      pk.x = (unsigned)f2bf(f0.x) | ((unsigned)f2bf(f0.y) << 16);
      pk.y = (unsigned)f2bf(f0.z) | ((unsigned)f2bf(f0.w) << 16);
      pk.z = (unsigned)f2bf(f1.x) | ((unsigned)f2bf(f1.y) << 16);
      pk.w = (unsigned)f2bf(f1.z) | ((unsigned)f2bf(f1.w) << 16);
      *(uint4*)(lds + rowb + (((unsigned)(p * 64 + kk * 16)) ^ sx)) = pk;
    }
  }
  __syncthreads();

  const unsigned sx31 = (unsigned)((l31 & 7) << 4);
  const int ntb = (w & 1) * 8;
  const int ksOff = (w >> 1) * 16;

  f32x16 acc[8];
#pragma unroll
  for (int f = 0; f < 8; ++f) {
    if (w < 2) {
      const int gf = w * 8 + f;
#pragma unroll
      for (int qd = 0; qd < 4; ++qd) {
        const float4 bq = *(const float4*)(b0 + gf * 32 + 8 * qd + 4 * h);
#pragma unroll
        for (int rr = 0; rr < 4; ++rr) acc[f][4 * qd + rr] = bq[rr];
      }
    } else {
#pragma unroll
      for (int i = 0; i < 16; ++i) acc[f][i] = 0.f;
    }
  }

#pragma unroll 2
  for (int ks = 0; ks < 16; ++ks) {
    const unsigned cb = (unsigned)(ks * 32 + h * 16);
    bf16x8 e0 = *(const bf16x8*)(lds + (unsigned)l31 * 512 + (cb ^ sx31));
#pragma unroll
    for (int f = 0; f < 8; ++f) {
      const bf16x8 wf = *(const bf16x8*)(wp +
          ((size_t)(((ntb + f) * 32) + ks + ksOff) * 64 + lane) * 8);
      acc[f] = __builtin_amdgcn_mfma_f32_32x32x16_bf16(wf, e0, acc[f], 0, 0, 0);
    }
  }

  {
    int node = n0 + l31; if (node > N_NODES - 1) node = N_NODES - 1;
    unsigned short* yrow = yab + (size_t)node * 1024;
#pragma unroll
    for (int f = 0; f < 8; ++f) {
      const int gf = w * 8 + f;
#pragma unroll
      for (int qd = 0; qd < 4; ++qd) {
        uint2 pk;
        pk.x = (unsigned)f2bf_cast(acc[f][4 * qd + 0]) |
               ((unsigned)f2bf_cast(acc[f][4 * qd + 1]) << 16);
        pk.y = (unsigned)f2bf_cast(acc[f][4 * qd + 2]) |
               ((unsigned)f2bf_cast(acc[f][4 * qd + 3]) << 16);
        *(uint2*)(yrow + gf * 32 + 8 * qd + 4 * h) = pk;
      }
    }
  }
}

// ===== counting-sort PAIRS by even-edge src node ============================
__global__ __launch_bounds__(256) void hist_pairs(
    const int* __restrict__ eidx, unsigned* __restrict__ hist) {
  int m = blockIdx.x * 256 + threadIdx.x;
  if (m < NPAIR) atomicAdd(&hist[eidx[2 * m]], 1u);
}
__global__ __launch_bounds__(1024) void scan_hist(unsigned* __restrict__ hist) {
  __shared__ unsigned part[1024];
  const int t = threadIdx.x;
  unsigned loc[10];
  unsigned s = 0;
#pragma unroll
  for (int i = 0; i < 10; ++i) {
    const int idx = t * 10 + i;
    unsigned v = (idx < N_NODES) ? hist[idx] : 0u;
    loc[i] = v; s += v;
  }
  part[t] = s;
  __syncthreads();
  for (int off = 1; off < 1024; off <<= 1) {
    unsigned v = (t >= off) ? part[t - off] : 0u;
    __syncthreads();
    part[t] += v;
    __syncthreads();
  }
  unsigned run = (t == 0) ? 0u : part[t - 1];
#pragma unroll
  for (int i = 0; i < 10; ++i) {
    const int idx = t * 10 + i;
    if (idx < N_NODES) { hist[idx] = run; run += loc[i]; }
  }
}
__global__ __launch_bounds__(256) void scatter_pairs(
    const int* __restrict__ eidx, unsigned* __restrict__ hist,
    unsigned* __restrict__ pperm) {
  int m = blockIdx.x * 256 + threadIdx.x;
  if (m < NPAIR) {
    unsigned pos = atomicAdd(&hist[eidx[2 * m]], 1u);
    pperm[pos] = (unsigned)m;
  }
}

// ---------------------------------------------------------------------------
// Edge kernel (layer-0 factored), 8-wave blocks, 2 blocks/CU, DEPTH-2 weight
// prefetch. SORTED=1: tile = 32 src-sorted PAIRS (slots 2u/2u+1 = pair
// members) -> pair-mean in-kernel (shfl_xor 1), direct scattered out stores
// (no outp/mean_pairs round trip). SORTED=0: slot=e, coalesced out stores.
// ---------------------------------------------------------------------------
template <int SORTED>
__global__ __launch_bounds__(512, 2) void edge_mlp2(
    const int* __restrict__ eidx, const unsigned* __restrict__ pperm,
    const float* __restrict__ b1, const float* __restrict__ b2,
    const unsigned short* __restrict__ wp,
    const unsigned short* __restrict__ yab, float* __restrict__ out) {
  __shared__ uint4 ldsv[4096 + 96];           // 65536 + 1280 + 256 B
  unsigned char* lds = (unsigned char*)ldsv;
  float* obuf = (float*)(lds + 65536);        // 64*5 f32
  int* eslot = (int*)(lds + 65536 + 1280);    // 64 global edge ids

  const int tid = threadIdx.x;
  const int lane = tid & 63;
  const int w = tid >> 6;                     // wave 0..7
  const int l31 = lane & 31, h = lane >> 5;
  const int l15 = lane & 15, q = lane >> 4;
  const unsigned t = blockIdx.x;
  const int phase = ((int)t >> 3) & 31;

  // ---- stage H0[64][512]: relu(ya[src] + yb[dst]); 8 threads/row ----
  {
    const int r = tid >> 3, p = tid & 7;
    const int s = (int)t * 64 + r;
    int e;
    if (SORTED) {
      const int pm = (int)pperm[s >> 1];
      e = 2 * pm + (s & 1);
      if (p == 0) eslot[r] = e;
    } else {
      e = s;
    }
    const int src = eidx[e];
    const int dst = eidx[E_TOTAL + e];
    const unsigned short* pa = yab + (size_t)src * 1024 + p * 64;
    const unsigned short* pb = yab + (size_t)dst * 1024 + 512 + p * 64;
    const unsigned rowb = (unsigned)r * 1024;
    const unsigned sx = (unsigned)((r & 7) << 4);
    const unsigned cb0 = (unsigned)(p * 128);
#pragma unroll
    for (int i = 0; i < 8; ++i) {
      const int kk = (i + p) & 7;             // phase by p: spread banks
      const uint4 a = *(const uint4*)(pa + kk * 8);
      const uint4 b = *(const uint4*)(pb + kk * 8);
      uint4 o;
      o.x = addrelu2(a.x, b.x);
      o.y = addrelu2(a.y, b.y);
      o.z = addrelu2(a.z, b.z);
      o.w = addrelu2(a.w, b.w);
      *(uint4*)(lds + rowb + ((cb0 + (unsigned)kk * 16) ^ sx)) = o;
    }
  }
  __syncthreads();

  const unsigned sx31 = (unsigned)((l31 & 7) << 4);
  const unsigned er0 = (unsigned)l31 * 1024;
  const unsigned er1 = (unsigned)(32 + l31) * 1024;

  // ===== hidden layer 1: wave w -> feature tiles 2w, 2w+1 x all 64 edges ====
  {
    const unsigned short* wl = wp + 262144;   // W1p
    const unsigned short* wbA = wl + (size_t)(2 * w) * 16384 + (size_t)lane * 8;
    const unsigned short* wbB = wbA + 16384;

    f32x16 aA0, aA1, aB0, aB1;                // acc[ftile][etile]
#define BINIT(ACC0, ACC1, F)                                                   \
    {                                                                          \
      _Pragma("unroll")                                                        \
      for (int qd = 0; qd < 4; ++qd) {                                         \
        const float4 bq = *(const float4*)(b1 + w * 64 + (F) * 32 + 8 * qd + 4 * h); \
        _Pragma("unroll")                                                      \
        for (int rr = 0; rr < 4; ++rr) {                                       \
          (ACC0)[4 * qd + rr] = bq[rr];                                        \
          (ACC1)[4 * qd + rr] = bq[rr];                                        \
        }                                                                      \
      }                                                                        \
    }
    BINIT(aA0, aA1, 0) BINIT(aB0, aB1, 1)
#undef BINIT

    // depth-2 weight prefetch prologue + 1-ahead e-frags
    bf16x8 cwA = *(const bf16x8*)(wbA + phase * 512);
    bf16x8 cwB = *(const bf16x8*)(wbB + phase * 512);
    const int ph1 = (phase + 1) & 31;
    bf16x8 nwA = *(const bf16x8*)(wbA + ph1 * 512);
    bf16x8 nwB = *(const bf16x8*)(wbB + ph1 * 512);
    const unsigned cb00 = (unsigned)(phase * 32 + h * 16);
    bf16x8 e0 = *(const bf16x8*)(lds + er0 + (cb00 ^ sx31));
    bf16x8 e1 = *(const bf16x8*)(lds + er1 + (cb00 ^ sx31));

#pragma unroll 2
    for (int i = 0; i < 32; ++i) {
      const int ks = (i + phase) & 31;
      const int kp1 = (ks + 1) & 31;          // e-frags for next iter
      const int kp2 = (ks + 2) & 31;          // weights two ahead
      bf16x8 tA = *(const bf16x8*)(wbA + kp2 * 512);
      bf16x8 tB = *(const bf16x8*)(wbB + kp2 * 512);
      const unsigned cbn = (unsigned)(kp1 * 32 + h * 16);
      bf16x8 ne0 = *(const bf16x8*)(lds + er0 + (cbn ^ sx31));
      bf16x8 ne1 = *(const bf16x8*)(lds + er1 + (cbn ^ sx31));
      aA0 = __builtin_amdgcn_mfma_f32_32x32x16_bf16(cwA, e0, aA0, 0, 0, 0);
      aB0 = __builtin_amdgcn_mfma_f32_32x32x16_bf16(cwB, e0, aB0, 0, 0, 0);
      aA1 = __builtin_amdgcn_mfma_f32_32x32x16_bf16(cwA, e1, aA1, 0, 0, 0);
      aB1 = __builtin_amdgcn_mfma_f32_32x32x16_bf16(cwB, e1, aB1, 0, 0, 0);
      cwA = nwA; cwB = nwB; nwA = tA; nwB = tB;
      e0 = ne0; e1 = ne1;
    }

    __syncthreads();

    // relu + cvt + write H over A, b64 quads (C: col=edge, row=feature)
#define EPI_TILE(ACC, F, ET)                                                   \
    {                                                                          \
      const unsigned rowb = (unsigned)((ET) * 32 + l31) * 1024;                \
      const unsigned cbase = (unsigned)(128 * w + 64 * (F) + 8 * h);           \
      _Pragma("unroll")                                                        \
      for (int qd = 0; qd < 4; ++qd) {                                         \
        uint2 pk2;                                                             \
        pk2.x = (unsigned)f2bf_cast(fmaxf((ACC)[4 * qd + 0], 0.f)) |           \
                ((unsigned)f2bf_cast(fmaxf((ACC)[4 * qd + 1], 0.f)) << 16);    \
        pk2.y = (unsigned)f2bf_cast(fmaxf((ACC)[4 * qd + 2], 0.f)) |           \
                ((unsigned)f2bf_cast(fmaxf((ACC)[4 * qd + 3], 0.f)) << 16);    \
        *(uint2*)(lds + rowb + ((cbase + 16u * qd) ^ sx31)) = pk2;             \
      }                                                                        \
    }
    EPI_TILE(aA0, 0, 0) EPI_TILE(aA1, 0, 1)
    EPI_TILE(aB0, 1, 0) EPI_TILE(aB1, 1, 1)
#undef EPI_TILE
    __syncthreads();
  }

  // ===== layer 2: waves 0..3 -> slots w*16..+15; pair-mean via shfl_xor(1) ==
  if (w < 4) {
    f32x4 acc2; acc2[0] = 0.f; acc2[1] = 0.f; acc2[2] = 0.f; acc2[3] = 0.f;
    const unsigned short* w2b = wp + 524288 + (size_t)lane * 8;
    const unsigned row = (unsigned)(w * 16 + l15);
    const unsigned rsx = (row & 7) << 4;
    const int ph16 = phase & 15;
#pragma unroll
    for (int i = 0; i < 16; ++i) {
      const int k0 = (i + ph16) & 15;
      bf16x8 eF = *(const bf16x8*)(lds + row * 1024 + (((unsigned)(k0 * 64 + q * 16)) ^ rsx));
      bf16x8 wF = *(const bf16x8*)(w2b + k0 * 512);
      acc2 = __builtin_amdgcn_mfma_f32_16x16x32_bf16(wF, eF, acc2, 0, 0, 0);
    }
    const int e = w * 16 + l15;                // block-local slot
#pragma unroll
    for (int r = 0; r < 4; ++r) {
      const float s = __shfl_xor(acc2[r], 1);  // pair partner (slot ^ 1)
      const float m = 0.5f * (acc2[r] + s);
      if (q == 0) obuf[e * OUTD + r] = m + b2[r];
      else if (q == 1 && r == 0) obuf[e * OUTD + 4] = m + b2[4];
    }
  }
  __syncthreads();

  // ===== out store =====
  if (SORTED) {
    // scattered per-edge 20B stores via eslot (both pair members hold mean)
    if (tid < 64) {
      const int eg = eslot[tid];
      const float* sob = obuf + tid * OUTD;
      float* og = out + (size_t)eg * OUTD;
#pragma unroll
      for (int i = 0; i < OUTD; ++i) og[i] = sob[i];
    }
  } else {
    uint4* dst = (uint4*)(out + (size_t)t * 320);
    const uint4* sob = (const uint4*)obuf;
    if (tid < 80) dst[tid] = sob[tid];
  }
}

extern "C" void kernel_launch(void* const* d_in, const int* in_sizes, int n_in,
                              void* d_out, int out_size, void* d_ws, size_t ws_size,
                              hipStream_t stream) {
  const float* x  = (const float*)d_in[0];
  const int* eidx = (const int*)d_in[1];
  const float* W0 = (const float*)d_in[2];
  const float* b0 = (const float*)d_in[3];
  const float* W1 = (const float*)d_in[4];
  const float* b1 = (const float*)d_in[5];
  const float* W2 = (const float*)d_in[6];
  const float* b2 = (const float*)d_in[7];
  float* out = (float*)d_out;
  unsigned short* wp = (unsigned short*)d_ws;
  if (ws_size < WS_Y) return;                 // need yab workspace

  const bool sorted = (ws_size >= WS_SORT);
  unsigned char* base = (unsigned char*)d_ws + WS_Y;
  unsigned* hist = sorted ? (unsigned*)base : nullptr;

  pack_weights<<<300, 256, 0, stream>>>(W0, W1, W2, wp, hist);
  unsigned short* yab = wp + WP_USHORTS;
  node_mlp0<<<313, 256, 0, stream>>>(x, b0, wp, yab);

  if (sorted) {
    unsigned* pperm = (unsigned*)(base + 40960);          // 100000 u32
    hist_pairs<<<391, 256, 0, stream>>>(eidx, hist);
    scan_hist<<<1, 1024, 0, stream>>>(hist);
    scatter_pairs<<<391, 256, 0, stream>>>(eidx, hist, pperm);
    edge_mlp2<1><<<NTILES, 512, 0, stream>>>(eidx, pperm, b1, b2, wp, yab, out);
  } else {
    edge_mlp2<0><<<NTILES, 512, 0, stream>>>(eidx, nullptr, b1, b2, wp, yab, out);
  }
}

// Round 24
// 218.911 us; speedup vs baseline: 1.0452x; 1.0452x over previous
//
#include <hip/hip_runtime.h>

#define E_TOTAL 200000
#define NPAIR 100000
#define N_NODES 10000
#define OUTD 5
#define NTILES 3125           // 200000 / 64 exactly
#define WP_USHORTS 532480     // W0p (262144) + W1p (262144) + W2p (8192)
#define YAB_USHORTS 10240000  // 10000 nodes x 1024 (ya|yb) bf16
#define WS_Y ((size_t)(WP_USHORTS + YAB_USHORTS) * 2)
// sort extras (bytes, after yab): hist u32[10240] | perm u32[200000] |
// rank u32[200000] | outp f32[1000000]
#define WS_SORT (WS_Y + 40960 + 800000 + 800000 + 4000000)

typedef __attribute__((ext_vector_type(4))) float f32x4;
typedef __attribute__((ext_vector_type(16))) float f32x16;
typedef __attribute__((ext_vector_type(8))) __bf16 bf16x8;

static __device__ __forceinline__ unsigned short f2bf(float f) {
  union { float f; unsigned u; } v; v.f = f;
  unsigned u = v.u;
  unsigned r = (u + 0x7FFFu + ((u >> 16) & 1u)) >> 16;   // RNE
  return (unsigned short)r;
}
static __device__ __forceinline__ unsigned short f2bf_cast(float f) {
  __bf16 h = (__bf16)f;                                   // HW cvt, RNE
  return __builtin_bit_cast(unsigned short, h);
}
static __device__ __forceinline__ unsigned addrelu2(unsigned a, unsigned b) {
  float alo = __builtin_bit_cast(float, a << 16);
  float ahi = __builtin_bit_cast(float, a & 0xffff0000u);
  float blo = __builtin_bit_cast(float, b << 16);
  float bhi = __builtin_bit_cast(float, b & 0xffff0000u);
  float slo = fmaxf(alo + blo, 0.f);
  float shi = fmaxf(ahi + bhi, 0.f);
  return (unsigned)f2bf_cast(slo) | ((unsigned)f2bf_cast(shi) << 16);
}

// ---------------------------------------------------------------------------
// Pack W0,W1 [512x512] into 32x32x16-bf16 fragment order; W2 padded N=16.
// One thread = one 16B chunk (8 coalesced f32 reads -> 1 uint4 store).
// FUSED: tid in [66560, 266560) does hist_src atomics (hist pre-zeroed by
// hipMemsetAsync) -- deletes one kernel launch.
// ---------------------------------------------------------------------------
__global__ __launch_bounds__(256) void pack_weights(
    const float* __restrict__ W0, const float* __restrict__ W1,
    const float* __restrict__ W2, unsigned short* __restrict__ wp,
    const int* __restrict__ eidx, unsigned* __restrict__ hist) {
  const int tid = blockIdx.x * 256 + threadIdx.x;
  if (tid < 65536) {
    const int sel = tid >> 15;
    const int r = tid & 32767;
    const int ntile = r >> 11;
    const int ks = (r >> 6) & 31;
    const int lane = r & 63;
    const float* W = sel ? W1 : W0;
    const int n = ntile * 32 + (lane & 31);
    const int kb = ks * 16 + ((lane >> 5) << 3);
    uint4 pk;
    pk.x = (unsigned)f2bf(W[(kb + 0) * 512 + n]) | ((unsigned)f2bf(W[(kb + 1) * 512 + n]) << 16);
    pk.y = (unsigned)f2bf(W[(kb + 2) * 512 + n]) | ((unsigned)f2bf(W[(kb + 3) * 512 + n]) << 16);
    pk.z = (unsigned)f2bf(W[(kb + 4) * 512 + n]) | ((unsigned)f2bf(W[(kb + 5) * 512 + n]) << 16);
    pk.w = (unsigned)f2bf(W[(kb + 6) * 512 + n]) | ((unsigned)f2bf(W[(kb + 7) * 512 + n]) << 16);
    *(uint4*)(wp + (size_t)sel * 262144 +
              (((size_t)(ntile * 32 + ks) * 64 + lane) << 3)) = pk;
  } else if (tid < 66560) {                    // W2 padded N=5 -> 16
    const int r = tid - 65536;
    const int k0 = r >> 6, lane = r & 63;
    const int kb = k0 * 32 + ((lane >> 4) << 3);
    const int n = lane & 15;
    unsigned short v[8];
#pragma unroll
    for (int j = 0; j < 8; ++j)
      v[j] = (n < OUTD) ? f2bf(W2[(kb + j) * OUTD + n]) : (unsigned short)0;
    uint4 pk;
    pk.x = (unsigned)v[0] | ((unsigned)v[1] << 16);
    pk.y = (unsigned)v[2] | ((unsigned)v[3] << 16);
    pk.z = (unsigned)v[4] | ((unsigned)v[5] << 16);
    pk.w = (unsigned)v[6] | ((unsigned)v[7] << 16);
    *(uint4*)(wp + 524288 + (((size_t)k0 * 64 + lane) << 3)) = pk;
  } else if (hist) {
    const int e = tid - 66560;
    if (e < E_TOTAL) atomicAdd(&hist[eidx[e]], 1u);
  }
}

// ---------------------------------------------------------------------------
// Node-level layer-0 precompute; packed uint2 stores.
// yab[node][0..512) = x@W0a + b0 ; [512..1024) = x@W0b.
// ---------------------------------------------------------------------------
__global__ __launch_bounds__(256, 2) void node_mlp0(
    const float* __restrict__ x, const float* __restrict__ b0,
    const unsigned short* __restrict__ wp, unsigned short* __restrict__ yab) {
  __shared__ uint4 ldsv2[1024];               // 16384 B
  unsigned char* lds = (unsigned char*)ldsv2;
  const int tid = threadIdx.x;
  const int lane = tid & 63;
  const int w = tid >> 6;
  const int l31 = lane & 31, h = lane >> 5;
  const int n0 = blockIdx.x * 32;

  {
    const int r = tid >> 3, p = tid & 7;
    int node = n0 + r; if (node > N_NODES - 1) node = N_NODES - 1;
    const float* s = x + (size_t)node * 256 + p * 32;
    const unsigned rowb = (unsigned)r * 512;
    const unsigned sx = (unsigned)((r & 7) << 4);
#pragma unroll
    for (int c = 0; c < 4; ++c) {
      const int kk = (c + p) & 3;
      const float4 f0 = *(const float4*)(s + kk * 8);
      const float4 f1 = *(const float4*)(s + kk * 8 + 4);
      uint4 pk;
      pk.x = (unsigned)f2bf(f0.x) | ((unsigned)f2bf(f0.y) << 16);
      pk.y = (unsigned)f2bf(f0.z) | ((unsigned)f2bf(f0.w) << 16);
      pk.z = (unsigned)f2bf(f1.x) | ((unsigned)f2bf(f1.y) << 16);
      pk.w = (unsigned)f2bf(f1.z) | ((unsigned)f2bf(f1.w) << 16);
      *(uint4*)(lds + rowb + (((unsigned)(p * 64 + kk * 16)) ^ sx)) = pk;
    }
  }
  __syncthreads();

  const unsigned sx31 = (unsigned)((l31 & 7) << 4);
  const int ntb = (w & 1) * 8;
  const int ksOff = (w >> 1) * 16;

  f32x16 acc[8];
#pragma unroll
  for (int f = 0; f < 8; ++f) {
    if (w < 2) {
      const int gf = w * 8 + f;
#pragma unroll
      for (int qd = 0; qd < 4; ++qd) {
        const float4 bq = *(const float4*)(b0 + gf * 32 + 8 * qd + 4 * h);
#pragma unroll
        for (int rr = 0; rr < 4; ++rr) acc[f][4 * qd + rr] = bq[rr];
      }
    } else {
#pragma unroll
      for (int i = 0; i < 16; ++i) acc[f][i] = 0.f;
    }
  }

#pragma unroll 2
  for (int ks = 0; ks < 16; ++ks) {
    const unsigned cb = (unsigned)(ks * 32 + h * 16);
    bf16x8 e0 = *(const bf16x8*)(lds + (unsigned)l31 * 512 + (cb ^ sx31));
#pragma unroll
    for (int f = 0; f < 8; ++f) {
      const bf16x8 wf = *(const bf16x8*)(wp +
          ((size_t)(((ntb + f) * 32) + ks + ksOff) * 64 + lane) * 8);
      acc[f] = __builtin_amdgcn_mfma_f32_32x32x16_bf16(wf, e0, acc[f], 0, 0, 0);
    }
  }

  {
    int node = n0 + l31; if (node > N_NODES - 1) node = N_NODES - 1;
    unsigned short* yrow = yab + (size_t)node * 1024;
#pragma unroll
    for (int f = 0; f < 8; ++f) {
      const int gf = w * 8 + f;
#pragma unroll
      for (int qd = 0; qd < 4; ++qd) {
        uint2 pk;
        pk.x = (unsigned)f2bf_cast(acc[f][4 * qd + 0]) |
               ((unsigned)f2bf_cast(acc[f][4 * qd + 1]) << 16);
        pk.y = (unsigned)f2bf_cast(acc[f][4 * qd + 2]) |
               ((unsigned)f2bf_cast(acc[f][4 * qd + 3]) << 16);
        *(uint2*)(yrow + gf * 32 + 8 * qd + 4 * h) = pk;
      }
    }
  }
}

// ===== counting-sort edges by src node (hist built in pack_weights) =========
__global__ __launch_bounds__(1024) void scan_hist(unsigned* __restrict__ hist) {
  __shared__ unsigned part[1024];
  const int t = threadIdx.x;
  unsigned loc[10];
  unsigned s = 0;
#pragma unroll
  for (int i = 0; i < 10; ++i) {
    const int idx = t * 10 + i;
    unsigned v = (idx < N_NODES) ? hist[idx] : 0u;
    loc[i] = v; s += v;
  }
  part[t] = s;
  __syncthreads();
  for (int off = 1; off < 1024; off <<= 1) {
    unsigned v = (t >= off) ? part[t - off] : 0u;
    __syncthreads();
    part[t] += v;
    __syncthreads();
  }
  unsigned run = (t == 0) ? 0u : part[t - 1];
#pragma unroll
  for (int i = 0; i < 10; ++i) {
    const int idx = t * 10 + i;
    if (idx < N_NODES) { hist[idx] = run; run += loc[i]; }
  }
}
__global__ __launch_bounds__(256) void scatter_perm(
    const int* __restrict__ eidx, unsigned* __restrict__ hist,
    unsigned* __restrict__ perm, unsigned* __restrict__ rank) {
  int e = blockIdx.x * 256 + threadIdx.x;
  if (e < E_TOTAL) {
    unsigned pos = atomicAdd(&hist[eidx[e]], 1u);
    perm[pos] = (unsigned)e;
    rank[e] = pos;
  }
}

// ---------------------------------------------------------------------------
// Edge kernel (layer-0 factored), 8-wave blocks, 2 blocks/CU (16 waves/CU),
// DEPTH-2 weight prefetch + 1-ahead e-frags. SORTED=1: slots src-sorted
// (perm), raw per-edge out to outp (coalesced); pair-mean in mean_pairs.
// SORTED=0: slot=e, pair-mean in-kernel.
// ---------------------------------------------------------------------------
template <int SORTED>
__global__ __launch_bounds__(512, 2) void edge_mlp2(
    const int* __restrict__ eidx, const unsigned* __restrict__ perm,
    const float* __restrict__ b1, const float* __restrict__ b2,
    const unsigned short* __restrict__ wp,
    const unsigned short* __restrict__ yab, float* __restrict__ dst5) {
  __shared__ uint4 ldsv[4096 + 80];           // 65536 + 1280 B
  unsigned char* lds = (unsigned char*)ldsv;
  float* obuf = (float*)(lds + 65536);        // 64*5 f32

  const int tid = threadIdx.x;
  const int lane = tid & 63;
  const int w = tid >> 6;                     // wave 0..7
  const int l31 = lane & 31, h = lane >> 5;
  const int l15 = lane & 15, q = lane >> 4;
  const unsigned t = blockIdx.x;
  const int phase = ((int)t >> 3) & 31;

  // ---- stage H0[64][512]: relu(ya[src] + yb[dst]); 8 threads/row ----
  {
    const int r = tid >> 3, p = tid & 7;
    const int s = (int)t * 64 + r;
    const int e = SORTED ? (int)perm[s] : s;
    const int src = eidx[e];
    const int dst = eidx[E_TOTAL + e];
    const unsigned short* pa = yab + (size_t)src * 1024 + p * 64;
    const unsigned short* pb = yab + (size_t)dst * 1024 + 512 + p * 64;
    const unsigned rowb = (unsigned)r * 1024;
    const unsigned sx = (unsigned)((r & 7) << 4);
    const unsigned cb0 = (unsigned)(p * 128);
#pragma unroll
    for (int i = 0; i < 8; ++i) {
      const int kk = (i + p) & 7;             // phase by p: spread banks
      const uint4 a = *(const uint4*)(pa + kk * 8);
      const uint4 b = *(const uint4*)(pb + kk * 8);
      uint4 o;
      o.x = addrelu2(a.x, b.x);
      o.y = addrelu2(a.y, b.y);
      o.z = addrelu2(a.z, b.z);
      o.w = addrelu2(a.w, b.w);
      *(uint4*)(lds + rowb + ((cb0 + (unsigned)kk * 16) ^ sx)) = o;
    }
  }
  __syncthreads();

  const unsigned sx31 = (unsigned)((l31 & 7) << 4);
  const unsigned er0 = (unsigned)l31 * 1024;
  const unsigned er1 = (unsigned)(32 + l31) * 1024;

  // ===== hidden layer 1: wave w -> feature tiles 2w, 2w+1 x all 64 edges ====
  {
    const unsigned short* wl = wp + 262144;   // W1p
    const unsigned short* wbA = wl + (size_t)(2 * w) * 16384 + (size_t)lane * 8;
    const unsigned short* wbB = wbA + 16384;

    f32x16 aA0, aA1, aB0, aB1;                // acc[ftile][etile]
#define BINIT(ACC0, ACC1, F)                                                   \
    {                                                                          \
      _Pragma("unroll")                                                        \
      for (int qd = 0; qd < 4; ++qd) {                                         \
        const float4 bq = *(const float4*)(b1 + w * 64 + (F) * 32 + 8 * qd + 4 * h); \
        _Pragma("unroll")                                                      \
        for (int rr = 0; rr < 4; ++rr) {                                       \
          (ACC0)[4 * qd + rr] = bq[rr];                                        \
          (ACC1)[4 * qd + rr] = bq[rr];                                        \
        }                                                                      \
      }                                                                        \
    }
    BINIT(aA0, aA1, 0) BINIT(aB0, aB1, 1)
#undef BINIT

    // depth-2 weight prefetch prologue + 1-ahead e-frags
    bf16x8 cwA = *(const bf16x8*)(wbA + phase * 512);
    bf16x8 cwB = *(const bf16x8*)(wbB + phase * 512);
    const int ph1 = (phase + 1) & 31;
    bf16x8 nwA = *(const bf16x8*)(wbA + ph1 * 512);
    bf16x8 nwB = *(const bf16x8*)(wbB + ph1 * 512);
    const unsigned cb00 = (unsigned)(phase * 32 + h * 16);
    bf16x8 e0 = *(const bf16x8*)(lds + er0 + (cb00 ^ sx31));
    bf16x8 e1 = *(const bf16x8*)(lds + er1 + (cb00 ^ sx31));

#pragma unroll 2
    for (int i = 0; i < 32; ++i) {
      const int ks = (i + phase) & 31;
      const int kp1 = (ks + 1) & 31;          // e-frags for next iter
      const int kp2 = (ks + 2) & 31;          // weights two ahead
      bf16x8 tA = *(const bf16x8*)(wbA + kp2 * 512);
      bf16x8 tB = *(const bf16x8*)(wbB + kp2 * 512);
      const unsigned cbn = (unsigned)(kp1 * 32 + h * 16);
      bf16x8 ne0 = *(const bf16x8*)(lds + er0 + (cbn ^ sx31));
      bf16x8 ne1 = *(const bf16x8*)(lds + er1 + (cbn ^ sx31));
      aA0 = __builtin_amdgcn_mfma_f32_32x32x16_bf16(cwA, e0, aA0, 0, 0, 0);
      aB0 = __builtin_amdgcn_mfma_f32_32x32x16_bf16(cwB, e0, aB0, 0, 0, 0);
      aA1 = __builtin_amdgcn_mfma_f32_32x32x16_bf16(cwA, e1, aA1, 0, 0, 0);
      aB1 = __builtin_amdgcn_mfma_f32_32x32x16_bf16(cwB, e1, aB1, 0, 0, 0);
      cwA = nwA; cwB = nwB; nwA = tA; nwB = tB;
      e0 = ne0; e1 = ne1;
    }

    __syncthreads();

    // relu + cvt + write H over A, b64 quads (C: col=edge, row=feature)
#define EPI_TILE(ACC, F, ET)                                                   \
    {                                                                          \
      const unsigned rowb = (unsigned)((ET) * 32 + l31) * 1024;                \
      const unsigned cbase = (unsigned)(128 * w + 64 * (F) + 8 * h);           \
      _Pragma("unroll")                                                        \
      for (int qd = 0; qd < 4; ++qd) {                                         \
        uint2 pk2;                                                             \
        pk2.x = (unsigned)f2bf_cast(fmaxf((ACC)[4 * qd + 0], 0.f)) |           \
                ((unsigned)f2bf_cast(fmaxf((ACC)[4 * qd + 1], 0.f)) << 16);    \
        pk2.y = (unsigned)f2bf_cast(fmaxf((ACC)[4 * qd + 2], 0.f)) |           \
                ((unsigned)f2bf_cast(fmaxf((ACC)[4 * qd + 3], 0.f)) << 16);    \
        *(uint2*)(lds + rowb + ((cbase + 16u * qd) ^ sx31)) = pk2;             \
      }                                                                        \
    }
    EPI_TILE(aA0, 0, 0) EPI_TILE(aA1, 0, 1)
    EPI_TILE(aB0, 1, 0) EPI_TILE(aB1, 1, 1)
#undef EPI_TILE
    __syncthreads();
  }

  // ===== layer 2: waves 0..3 -> slots w*16..+15 =====
  if (w < 4) {
    f32x4 acc2; acc2[0] = 0.f; acc2[1] = 0.f; acc2[2] = 0.f; acc2[3] = 0.f;
    const unsigned short* w2b = wp + 524288 + (size_t)lane * 8;
    const unsigned row = (unsigned)(w * 16 + l15);
    const unsigned rsx = (row & 7) << 4;
    const int ph16 = phase & 15;
#pragma unroll
    for (int i = 0; i < 16; ++i) {
      const int k0 = (i + ph16) & 15;
      bf16x8 eF = *(const bf16x8*)(lds + row * 1024 + (((unsigned)(k0 * 64 + q * 16)) ^ rsx));
      bf16x8 wF = *(const bf16x8*)(w2b + k0 * 512);
      acc2 = __builtin_amdgcn_mfma_f32_16x16x32_bf16(wF, eF, acc2, 0, 0, 0);
    }
    const int e = w * 16 + l15;                // block-local slot
    if (SORTED) {
#pragma unroll
      for (int r = 0; r < 4; ++r) {
        if (q == 0) obuf[e * OUTD + r] = acc2[r] + b2[r];
        else if (q == 1 && r == 0) obuf[e * OUTD + 4] = acc2[0] + b2[4];
      }
    } else {
#pragma unroll
      for (int r = 0; r < 4; ++r) {
        const float s = __shfl_xor(acc2[r], 1);
        const float m = 0.5f * (acc2[r] + s);
        if (q == 0) obuf[e * OUTD + r] = m + b2[r];
        else if (q == 1 && r == 0) obuf[e * OUTD + 4] = m + b2[4];
      }
    }
  }
  __syncthreads();

  // ===== coalesced store (20 full 64B lines) to outp (SORTED) or out =====
  {
    uint4* dst = (uint4*)(dst5 + (size_t)t * 320);
    const uint4* sob = (const uint4*)obuf;
    if (tid < 80) dst[tid] = sob[tid];
  }
}

// pair-mean epilogue: out[2m] = out[2m+1] = 0.5*(outp[rank[2m]]+outp[rank[2m+1]])
__global__ __launch_bounds__(256) void mean_pairs(
    const unsigned* __restrict__ rank, const float* __restrict__ outp,
    float* __restrict__ out) {
  int m = blockIdx.x * 256 + threadIdx.x;
  if (m < NPAIR) {
    const float* p0 = outp + (size_t)rank[2 * m] * OUTD;
    const float* p1 = outp + (size_t)rank[2 * m + 1] * OUTD;
    float v[OUTD];
#pragma unroll
    for (int i = 0; i < OUTD; ++i) v[i] = 0.5f * (p0[i] + p1[i]);
    float* o = out + (size_t)m * 2 * OUTD;
#pragma unroll
    for (int i = 0; i < OUTD; ++i) { o[i] = v[i]; o[OUTD + i] = v[i]; }
  }
}

extern "C" void kernel_launch(void* const* d_in, const int* in_sizes, int n_in,
                              void* d_out, int out_size, void* d_ws, size_t ws_size,
                              hipStream_t stream) {
  const float* x  = (const float*)d_in[0];
  const int* eidx = (const int*)d_in[1];
  const float* W0 = (const float*)d_in[2];
  const float* b0 = (const float*)d_in[3];
  const float* W1 = (const float*)d_in[4];
  const float* b1 = (const float*)d_in[5];
  const float* W2 = (const float*)d_in[6];
  const float* b2 = (const float*)d_in[7];
  float* out = (float*)d_out;
  unsigned short* wp = (unsigned short*)d_ws;
  if (ws_size < WS_Y) return;                 // need yab workspace

  const bool sorted = (ws_size >= WS_SORT);
  unsigned char* base = (unsigned char*)d_ws + WS_Y;
  unsigned* hist = sorted ? (unsigned*)base : nullptr;

  if (sorted) hipMemsetAsync(hist, 0, 40960, stream);
  pack_weights<<<1042, 256, 0, stream>>>(W0, W1, W2, wp, eidx, hist);
  unsigned short* yab = wp + WP_USHORTS;
  node_mlp0<<<313, 256, 0, stream>>>(x, b0, wp, yab);

  if (sorted) {
    unsigned* perm = (unsigned*)(base + 40960);           // 200000 u32
    unsigned* rank = (unsigned*)(base + 40960 + 800000);  // 200000 u32
    float* outp = (float*)(base + 40960 + 1600000);       // 1e6 f32

    scan_hist<<<1, 1024, 0, stream>>>(hist);
    scatter_perm<<<782, 256, 0, stream>>>(eidx, hist, perm, rank);
    edge_mlp2<1><<<NTILES, 512, 0, stream>>>(eidx, perm, b1, b2, wp, yab, outp);
    mean_pairs<<<391, 256, 0, stream>>>(rank, outp, out);
  } else {
    edge_mlp2<0><<<NTILES, 512, 0, stream>>>(eidx, nullptr, b1, b2, wp, yab, out);
  }
}